// Round 7
// baseline (280.814 us; speedup 1.0000x reference)
//
#include <hip/hip_runtime.h>
#include <stdint.h>

#define NN 50000
#define NE 800000
#define FD 64
#define HD 128
#define NBKT 196          // (NN+255)/256 coarse buckets (256 nodes each)
#define BCAP 5120         // per-bucket capacity (avg 4096, generous slack)
#define P1E 4096          // edges per pass-1 block (196 blocks: sort parallelism)

static_assert(NN % 16 == 0, "16-row tiles are exact");

typedef __attribute__((ext_vector_type(8))) short short8;   // 8 bf16 (4 VGPRs)
typedef __attribute__((ext_vector_type(4))) float f32x4;    // MFMA acc

#define AS1 __attribute__((address_space(1)))
#define AS3 __attribute__((address_space(3)))

// ---------- bf16 helpers ----------
__device__ __forceinline__ float bflo(unsigned int v) {
    union { unsigned int u; float f; } c; c.u = v << 16; return c.f;
}
__device__ __forceinline__ float bfhi(unsigned int v) {
    union { unsigned int u; float f; } c; c.u = v & 0xffff0000u; return c.f;
}
__device__ __forceinline__ unsigned short f2bf(float f) {
    union { float f; unsigned int u; } c; c.f = f;
    unsigned int u = c.u;
    return (unsigned short)((u + 0x7fffu + ((u >> 16) & 1u)) >> 16);
}
__device__ __forceinline__ unsigned int pack2(float a, float b) {
    return (unsigned int)f2bf(a) | ((unsigned int)f2bf(b) << 16);
}

// ---------- MFMA GEMM device body (k1 enc1 only; WCVT = inline f32->bf16 swizzle) ----------
template <int K, int COLS, int EPI, bool BIAS, bool A_F32, bool WCVT>
__device__ __forceinline__ void mgemm_dev(
    int bid,
    const void* __restrict__ Av,
    const void* __restrict__ Wt,
    const float* __restrict__ bias,
    void* __restrict__ outv, int nrows)
{
    constexpr int NB = COLS / 16;
    constexpr int KC = K / 32;
    constexpr int GMASK = (K >> 3) - 1;
    __shared__ __align__(16) unsigned char Ws8[COLS * K * 2];

    const int tid = threadIdx.x;
    const int wave = tid >> 6;
    const int lane = tid & 63;

    if constexpr (WCVT) {
        const float* wf = (const float*)Wt;
        unsigned short* ws = (unsigned short*)Ws8;
        #pragma unroll
        for (int i = 0; i < K * COLS / 256; i++) {
            const int e = i * 256 + tid;
            const int k = e / COLS, c = e % COLS;
            const int gsw = (k >> 3) ^ (c & GMASK);
            ws[c * K + gsw * 8 + (k & 7)] = f2bf(wf[e]);
        }
    } else {
        constexpr int ROUNDS = COLS * K * 2 / 4096;
        const int gb = wave * 1024 + lane * 16;
        const int lb = wave * 1024;
        #pragma unroll
        for (int r = 0; r < ROUNDS; r++) {
            __builtin_amdgcn_global_load_lds(
                (const AS1 unsigned int*)((const unsigned char*)Wt + r * 4096 + gb),
                (AS3 unsigned int*)(Ws8 + r * 4096 + lb),
                16, 0, 0);
        }
    }

    const int m = lane & 15;
    const int q = lane >> 4;
    const int row0 = bid * 64 + wave * 16;

    f32x4 acc[NB];
    #pragma unroll
    for (int i = 0; i < NB; i++) acc[i] = (f32x4){0.f, 0.f, 0.f, 0.f};

    const bool arow_ok = !A_F32 || (row0 + m) < nrows;

    short8 af[KC];
    #pragma unroll
    for (int kc = 0; kc < KC; kc++) {
        if constexpr (A_F32) {
            const float* arowf = (const float*)Av + (size_t)(row0 + m) * K + q * 8 + kc * 32;
            float4 lo = make_float4(0.f, 0.f, 0.f, 0.f), hi = lo;
            if (arow_ok) { lo = *(const float4*)arowf; hi = *(const float4*)(arowf + 4); }
            af[kc][0] = (short)f2bf(lo.x); af[kc][1] = (short)f2bf(lo.y);
            af[kc][2] = (short)f2bf(lo.z); af[kc][3] = (short)f2bf(lo.w);
            af[kc][4] = (short)f2bf(hi.x); af[kc][5] = (short)f2bf(hi.y);
            af[kc][6] = (short)f2bf(hi.z); af[kc][7] = (short)f2bf(hi.w);
        } else {
            const unsigned short* arow = (const unsigned short*)Av + (size_t)(row0 + m) * K + q * 8 + kc * 32;
            af[kc] = *(const short8*)arow;
        }
    }
    __syncthreads();

    #pragma unroll
    for (int kc = 0; kc < KC; kc++) {
        #pragma unroll
        for (int nb = 0; nb < NB; nb++) {
            const int c = nb * 16 + m;
            const int gsw = (kc * 4 + q) ^ (c & GMASK);
            short8 bf = *(const short8*)&Ws8[(c * K + gsw * 8) * 2];
            acc[nb] = __builtin_amdgcn_mfma_f32_16x16x32_bf16(af[kc], bf, acc[nb], 0, 0, 0);
        }
    }

    float bv[NB];
    #pragma unroll
    for (int nb = 0; nb < NB; nb++) bv[nb] = BIAS ? bias[nb * 16 + m] : 0.f;

    #pragma unroll
    for (int r = 0; r < 4; r++) {
        int row = row0 + q * 4 + r;
        if (row < nrows) {
            #pragma unroll
            for (int nb = 0; nb < NB; nb++) {
                float t = acc[nb][r] + bv[nb];
                if (EPI == 1) t = fmaxf(t, 0.f);
                ((unsigned short*)outv)[(size_t)row * COLS + nb * 16 + m] = f2bf(t);
            }
        }
    }
}

// ---------- K1: enc1-mgemm (inline W-convert) ∥ counting-sort pass 1 ∥ t1-t6 transposes ----------
// Entry pack: src(16b) | dlow(8b)<<16 | bkt(8b)<<24.
__global__ __launch_bounds__(256) void k1_k(
    const float* __restrict__ x, const float* __restrict__ w0,
    const float* __restrict__ enc_b1, unsigned short* __restrict__ bufA,
    const int* __restrict__ src, const int* __restrict__ dst,
    int* __restrict__ gcnt, unsigned int* __restrict__ bucket,
    const float* __restrict__ w1, const float* __restrict__ w2,
    const float* __restrict__ w3, const float* __restrict__ w4,
    const float* __restrict__ w5, const float* __restrict__ w6,
    unsigned short* __restrict__ t1, unsigned short* __restrict__ t2,
    unsigned short* __restrict__ t3, unsigned short* __restrict__ t4,
    unsigned short* __restrict__ t5, unsigned short* __restrict__ t6,
    int gb, int pb)
{
    const int b = blockIdx.x;
    if (b < gb) {
        mgemm_dev<64, 128, 1, true, true, true>(b, x, w0, enc_b1, bufA, NN);
    } else if (b < gb + pb) {
        __shared__ int lcnt[256], lsw[256], lexc[256], lofs[256], lrank[256];
        __shared__ unsigned int stage[P1E];
        const int tid = threadIdx.x;
        const int bb = b - gb;
        lcnt[tid] = 0; lrank[tid] = 0;
        __syncthreads();
        unsigned int ent[P1E / 256];
        #pragma unroll
        for (int u = 0; u < P1E / 256; u++) {
            int g = bb * P1E + u * 256 + tid;
            if (g < NE) {
                int d = dst[g], s = src[g];
                int bk = d >> 8;
                atomicAdd(&lcnt[bk], 1);
                ent[u] = (unsigned int)s | ((unsigned int)(d & 255) << 16)
                       | ((unsigned int)bk << 24);
            } else ent[u] = 0xFFFFFFFFu;
        }
        __syncthreads();
        int v = lcnt[tid];
        lsw[tid] = v; __syncthreads();
        for (int d = 1; d < 256; d <<= 1) {
            int xx = (tid >= d) ? lsw[tid - d] : 0; __syncthreads();
            lsw[tid] += xx; __syncthreads();
        }
        lexc[tid] = lsw[tid] - v;
        lofs[tid] = (v > 0) ? atomicAdd(&gcnt[tid], v) : 0;
        __syncthreads();
        #pragma unroll
        for (int u = 0; u < P1E / 256; u++) {
            if (ent[u] != 0xFFFFFFFFu) {
                int bk = ent[u] >> 24;
                int r = atomicAdd(&lrank[bk], 1);
                stage[lexc[bk] + r] = ent[u];
            }
        }
        __syncthreads();
        int cb = NE - bb * P1E; if (cb > P1E) cb = P1E;
        for (int i = tid; i < cb; i += 256) {
            unsigned int e = stage[i];
            int bk = e >> 24;
            bucket[(size_t)bk * BCAP + lofs[bk] + (i - lexc[bk])] = e;
        }
    } else {
        int b2 = b - gb - pb;       // 352 transpose blocks
        const float* W; unsigned short* T; int C = 128;
        if      (b2 <  64) { W = w1; T = t1; }
        else if (b2 < 128) { W = w2; T = t2; b2 -= 64; }
        else if (b2 < 192) { W = w3; T = t3; b2 -= 128; }
        else if (b2 < 256) { W = w4; T = t4; b2 -= 192; }
        else if (b2 < 320) { W = w5; T = t5; b2 -= 256; }
        else               { W = w6; T = t6; b2 -= 320; C = 64; }
        int e = b2 * 256 + threadIdx.x;
        int k, c;
        if (C == 128) { k = e >> 7; c = e & 127; } else { k = e >> 6; c = e & 63; }
        int gsw = (k >> 3) ^ (c & 15);   // K=128 -> gmask 15
        T[c * 128 + gsw * 8 + (k & 7)] = f2bf(W[e]);
    }
}

// ---------- K2f: fused enc2+conv1 double-GEMM (16-row tiles) ∥ pass 2 ----------
// gemm1 (transposed, validated r1/r4/r5): h2^T = enc_w2^T · h1^T via mfma(Wf, gf),
// gf loaded straight from global bufA rows. Pack h2 (+enc_b2, no relu) to LDS.
// gemm2 standard: bufB = h2 @ w_c1  (UNSCALED -> no dinv dependency; conv2's
// gather applies dinv[src] per edge).
__global__ __launch_bounds__(256) void k2f_k(
    const unsigned short* __restrict__ bufA, const unsigned short* __restrict__ t1,
    const float* __restrict__ enc_b2, const unsigned short* __restrict__ t2,
    unsigned short* __restrict__ bufB,
    const int* __restrict__ gcnt, const unsigned int* __restrict__ bucket,
    int* __restrict__ off, float* __restrict__ dinv,
    unsigned short* __restrict__ csr, int gb)
{
    if ((int)blockIdx.x < gb) {
        __shared__ __align__(16) uint4 h4[16 * 16];   // 4 KB h2 tile
        const int tid = threadIdx.x;
        const int wave = tid >> 6;
        const int lane = tid & 63;
        const int m = lane & 15;
        const int q = lane >> 4;
        const int row0 = blockIdx.x * 16;

        // Wf from t1 (enc_w2^T), rows c = wave*32+m (+16)
        short8 Wf0[4], Wf1[4];
        #pragma unroll
        for (int kc = 0; kc < 4; kc++) {
            const int c0 = wave * 32 + m;
            const int c1 = c0 + 16;
            Wf0[kc] = *(const short8*)&t1[c0 * 128 + (((kc * 4 + q) ^ (c0 & 15)) << 3)];
            Wf1[kc] = *(const short8*)&t1[c1 * 128 + (((kc * 4 + q) ^ (c1 & 15)) << 3)];
        }

        // gemm1 transposed: gf = h1 row m (global, linear chunks)
        f32x4 at0 = (f32x4){0.f, 0.f, 0.f, 0.f}, at1 = at0;
        #pragma unroll
        for (int kc = 0; kc < 4; kc++) {
            short8 gf = *(const short8*)&bufA[(size_t)(row0 + m) * 128 + ((q + kc * 4) << 3)];
            at0 = __builtin_amdgcn_mfma_f32_16x16x32_bf16(Wf0[kc], gf, at0, 0, 0, 0);
            at1 = __builtin_amdgcn_mfma_f32_16x16x32_bf16(Wf1[kc], gf, at1, 0, 0, 0);
        }

        // h-pack: lane (q,m) holds h2[node m][F..F+3]; +enc_b2, NO relu
        {
            uint2* h2 = (uint2*)h4;
            {   // f2 = 0
                const int F = wave * 32 + q * 4;
                const float4 bb = *(const float4*)(enc_b2 + F);
                uint2 hv;
                hv.x = pack2(at0[0] + bb.x, at0[1] + bb.y);
                hv.y = pack2(at0[2] + bb.z, at0[3] + bb.w);
                const int cf = wave * 4 + (q >> 1);
                h2[m * 32 + (((cf ^ m) << 1) | (q & 1))] = hv;
            }
            {   // f2 = 1
                const int F = wave * 32 + 16 + q * 4;
                const float4 bb = *(const float4*)(enc_b2 + F);
                uint2 hv;
                hv.x = pack2(at1[0] + bb.x, at1[1] + bb.y);
                hv.y = pack2(at1[2] + bb.z, at1[3] + bb.w);
                const int cf = wave * 4 + 2 + (q >> 1);
                h2[m * 32 + (((cf ^ m) << 1) | (q & 1))] = hv;
            }
        }
        __syncthreads();

        // gemm2 standard: Bf from t2 (w_c1^T), wave owns cols [wave*32, +32)
        short8 Bf0[4], Bf1[4];
        #pragma unroll
        for (int kc = 0; kc < 4; kc++) {
            const int c0 = wave * 32 + m;
            const int c1 = c0 + 16;
            Bf0[kc] = *(const short8*)&t2[c0 * 128 + (((kc * 4 + q) ^ (c0 & 15)) << 3)];
            Bf1[kc] = *(const short8*)&t2[c1 * 128 + (((kc * 4 + q) ^ (c1 & 15)) << 3)];
        }
        f32x4 a0 = (f32x4){0.f, 0.f, 0.f, 0.f}, a1 = a0;
        #pragma unroll
        for (int kc = 0; kc < 4; kc++) {
            short8 af = *(const short8*)&h4[m * 16 + ((q + kc * 4) ^ m)];
            a0 = __builtin_amdgcn_mfma_f32_16x16x32_bf16(af, Bf0[kc], a0, 0, 0, 0);
            a1 = __builtin_amdgcn_mfma_f32_16x16x32_bf16(af, Bf1[kc], a1, 0, 0, 0);
        }
        const int c0 = wave * 32 + m;
        const int c1 = c0 + 16;
        #pragma unroll
        for (int r = 0; r < 4; r++) {
            const int row = row0 + q * 4 + r;
            bufB[(size_t)row * 128 + c0] = f2bf(a0[r]);
            bufB[(size_t)row * 128 + c1] = f2bf(a1[r]);
        }
    } else {
        __shared__ int lc[256], sw[256], sexc[256], lr[256], gsh[256];
        const int tid = threadIdx.x;
        const int b = blockIdx.x - gb;
        int gv = (tid < NBKT) ? gcnt[tid] : 0;
        gsh[tid] = gv; __syncthreads();
        for (int d = 1; d < 256; d <<= 1) {
            int xx = (tid >= d) ? gsh[tid - d] : 0; __syncthreads();
            gsh[tid] += xx; __syncthreads();
        }
        const int cb = gcnt[b];
        const int base = gsh[b] - cb;
        unsigned int ent[BCAP / 256];
        #pragma unroll
        for (int u = 0; u < BCAP / 256; u++) {
            int i = u * 256 + tid;
            ent[u] = (i < cb) ? bucket[(size_t)b * BCAP + i] : 0xFFFFFFFFu;
        }
        lc[tid] = 0; lr[tid] = 0;
        __syncthreads();
        #pragma unroll
        for (int u = 0; u < BCAP / 256; u++)
            if (ent[u] != 0xFFFFFFFFu) atomicAdd(&lc[(ent[u] >> 16) & 255], 1);
        __syncthreads();
        int v = lc[tid];
        int node = b * 256 + tid;
        if (node < NN) dinv[node] = rsqrtf((float)(v + 1));  // +1 self-loop
        sw[tid] = v; __syncthreads();
        for (int d = 1; d < 256; d <<= 1) {
            int xx = (tid >= d) ? sw[tid - d] : 0; __syncthreads();
            sw[tid] += xx; __syncthreads();
        }
        sexc[tid] = sw[tid] - v;
        if (node < NN) off[node] = base + sexc[tid];
        if (b == NBKT - 1 && tid == 0) off[NN] = NE;
        __syncthreads();
        #pragma unroll
        for (int u = 0; u < BCAP / 256; u++) {
            if (ent[u] != 0xFFFFFFFFu) {
                int dl = (ent[u] >> 16) & 255;
                int r = atomicAdd(&lr[dl], 1);
                csr[base + sexc[dl] + r] = (unsigned short)(ent[u] & 0xffff);
            }
        }
    }
}

// ---------- gather, one node per 16-lane group (round-2/4 proven plain form) ----------
// WEIGHTED: input rows are unscaled -> multiply each gathered row by dinv[src]
// (16-lane broadcast load); self term by dinv[row].
template <bool WEIGHTED>
__device__ __forceinline__ void gather16_dev(
    const uint4* __restrict__ hws, const int* __restrict__ off,
    const unsigned short* __restrict__ csr, const float* __restrict__ dinv,
    const float* __restrict__ gbias, uint4* __restrict__ g4, int bid, int tid)
{
    const int g = tid >> 4;     // 0..15 = row in tile
    const int l = tid & 15;     // feature chunk (8 bf16)
    const int row = bid * 16 + g;               // always < NN (exact grid)
    const float4 b0 = *(const float4*)(gbias + 8 * l);
    const float4 b1 = *(const float4*)(gbias + 8 * l + 4);

    const float di = dinv[row];
    uint4 v = hws[(size_t)row * 16 + l];        // self-loop term
    const float ws = WEIGHTED ? di : 1.f;
    float s0 = ws * bflo(v.x), s1 = ws * bfhi(v.x), s2 = ws * bflo(v.y), s3 = ws * bfhi(v.y);
    float s4 = ws * bflo(v.z), s5 = ws * bfhi(v.z), s6 = ws * bflo(v.w), s7 = ws * bfhi(v.w);
    const int je = off[row + 1];
    int j = off[row];
    for (; j + 8 <= je; j += 8) {
        uint4 t[8]; float dw[8];
        #pragma unroll
        for (int u = 0; u < 8; u++) {
            const int idx = (int)csr[j + u];
            t[u] = hws[(size_t)idx * 16 + l];
            if constexpr (WEIGHTED) dw[u] = dinv[idx];
        }
        #pragma unroll
        for (int u = 0; u < 8; u++) {
            if constexpr (WEIGHTED) {
                const float w = dw[u];
                s0 = fmaf(w, bflo(t[u].x), s0); s1 = fmaf(w, bfhi(t[u].x), s1);
                s2 = fmaf(w, bflo(t[u].y), s2); s3 = fmaf(w, bfhi(t[u].y), s3);
                s4 = fmaf(w, bflo(t[u].z), s4); s5 = fmaf(w, bfhi(t[u].z), s5);
                s6 = fmaf(w, bflo(t[u].w), s6); s7 = fmaf(w, bfhi(t[u].w), s7);
            } else {
                s0 += bflo(t[u].x); s1 += bfhi(t[u].x);
                s2 += bflo(t[u].y); s3 += bfhi(t[u].y);
                s4 += bflo(t[u].z); s5 += bfhi(t[u].z);
                s6 += bflo(t[u].w); s7 += bfhi(t[u].w);
            }
        }
    }
    for (; j < je; j++) {
        const int idx = (int)csr[j];
        uint4 t = hws[(size_t)idx * 16 + l];
        const float w = WEIGHTED ? dinv[idx] : 1.f;
        s0 = fmaf(w, bflo(t.x), s0); s1 = fmaf(w, bfhi(t.x), s1);
        s2 = fmaf(w, bflo(t.y), s2); s3 = fmaf(w, bfhi(t.y), s3);
        s4 = fmaf(w, bflo(t.z), s4); s5 = fmaf(w, bfhi(t.z), s5);
        s6 = fmaf(w, bflo(t.w), s6); s7 = fmaf(w, bfhi(t.w), s7);
    }
    uint4 o;
    o.x = pack2(fmaxf(fmaf(di, s0, b0.x), 0.f), fmaxf(fmaf(di, s1, b0.y), 0.f));
    o.y = pack2(fmaxf(fmaf(di, s2, b0.z), 0.f), fmaxf(fmaf(di, s3, b0.w), 0.f));
    o.z = pack2(fmaxf(fmaf(di, s4, b1.x), 0.f), fmaxf(fmaf(di, s5, b1.y), 0.f));
    o.w = pack2(fmaxf(fmaf(di, s6, b1.z), 0.f), fmaxf(fmaf(di, s7, b1.w), 0.f));
    g4[g * 16 + (l ^ g)] = o;   // chunk l of row g stored at slot l^g
}

// ---------- fused agg + conv-GEMM, 16-row tiles ----------
template <bool WEIGHTED>
__global__ __launch_bounds__(256) void aggm16_k(
    const uint4* __restrict__ hws, const int* __restrict__ off,
    const unsigned short* __restrict__ csr, const float* __restrict__ dinv,
    const float* __restrict__ gbias,          // gather bias (b_c*)
    const unsigned short* __restrict__ Wt,    // W^T, XOR-swizzled layout (gmask 15)
    unsigned short* __restrict__ out)
{
    __shared__ __align__(16) uint4 g4[16 * 16];   // 4 KB A-tile

    const int tid = threadIdx.x;
    const int bid = blockIdx.x;
    const int wave = tid >> 6;
    const int lane = tid & 63;
    const int m = lane & 15;
    const int q = lane >> 4;

    // prestage B fragments (issued before gather; latency hidden under it)
    short8 Bf0[4], Bf1[4];
    #pragma unroll
    for (int kc = 0; kc < 4; kc++) {
        const int c0 = wave * 32 + m;
        const int c1 = c0 + 16;
        Bf0[kc] = *(const short8*)&Wt[c0 * 128 + (((kc * 4 + q) ^ (c0 & 15)) << 3)];
        Bf1[kc] = *(const short8*)&Wt[c1 * 128 + (((kc * 4 + q) ^ (c1 & 15)) << 3)];
    }

    gather16_dev<WEIGHTED>(hws, off, csr, dinv, gbias, g4, bid, tid);
    __syncthreads();

    // ---- GEMM: 16 rows x 128 cols, wave w owns cols [w*32, w*32+32) ----
    f32x4 a0 = (f32x4){0.f, 0.f, 0.f, 0.f}, a1 = a0;
    #pragma unroll
    for (int kc = 0; kc < 4; kc++) {
        short8 af = *(const short8*)&g4[m * 16 + ((q + kc * 4) ^ m)];
        a0 = __builtin_amdgcn_mfma_f32_16x16x32_bf16(af, Bf0[kc], a0, 0, 0, 0);
        a1 = __builtin_amdgcn_mfma_f32_16x16x32_bf16(af, Bf1[kc], a1, 0, 0, 0);
    }

    const int c0 = wave * 32 + m;
    const int c1 = c0 + 16;
    #pragma unroll
    for (int r = 0; r < 4; r++) {
        const int row = bid * 16 + q * 4 + r;
        const float sc = dinv[row];   // output pre-scaled for next (unweighted) gather
        out[(size_t)row * 128 + c0] = f2bf(a0[r] * sc);
        out[(size_t)row * 128 + c1] = f2bf(a1[r] * sc);
    }
}

// ---------- fused agg + full decoder (dec1 relu + dec2 sigmoid), 16-row tiles ----------
__global__ __launch_bounds__(256) void decf16_k(
    const uint4* __restrict__ hws, const int* __restrict__ off,
    const unsigned short* __restrict__ csr, const float* __restrict__ dinv,
    const float* __restrict__ gbias,          // b_c3
    const unsigned short* __restrict__ Wt1,   // dec_w1^T swizzled (128 cols)
    const float* __restrict__ db1,
    const unsigned short* __restrict__ Wt2,   // dec_w2^T swizzled (64 cols)
    const float* __restrict__ db2,
    float* __restrict__ outp)
{
    __shared__ __align__(16) uint4 g4[16 * 16];   // 4 KB gather tile
    __shared__ __align__(16) uint4 h4[16 * 16];   // 4 KB h tile

    const int tid = threadIdx.x;
    const int bid = blockIdx.x;
    const int wave = tid >> 6;
    const int lane = tid & 63;
    const int m = lane & 15;
    const int q = lane >> 4;

    // prestage dec_w1^T fragments (A'-operand of transposed product)
    short8 Wf0[4], Wf1[4];
    #pragma unroll
    for (int kc = 0; kc < 4; kc++) {
        const int c0 = wave * 32 + m;
        const int c1 = c0 + 16;
        Wf0[kc] = *(const short8*)&Wt1[c0 * 128 + (((kc * 4 + q) ^ (c0 & 15)) << 3)];
        Wf1[kc] = *(const short8*)&Wt1[c1 * 128 + (((kc * 4 + q) ^ (c1 & 15)) << 3)];
    }

    gather16_dev<false>(hws, off, csr, dinv, gbias, g4, bid, tid);
    __syncthreads();

    // ---- gemm1 (transposed): wave owns features [wave*32, wave*32+32) x 16 nodes ----
    f32x4 at0 = (f32x4){0.f, 0.f, 0.f, 0.f}, at1 = at0;
    #pragma unroll
    for (int kc = 0; kc < 4; kc++) {
        short8 gf = *(const short8*)&g4[m * 16 + ((q + kc * 4) ^ m)];
        at0 = __builtin_amdgcn_mfma_f32_16x16x32_bf16(Wf0[kc], gf, at0, 0, 0, 0);
        at1 = __builtin_amdgcn_mfma_f32_16x16x32_bf16(Wf1[kc], gf, at1, 0, 0, 0);
    }

    // prestage dec_w2^T B fragments (global, L2-hot; hidden under h-pack)
    short8 Bf2[4];
    #pragma unroll
    for (int kc = 0; kc < 4; kc++) {
        const int c = wave * 16 + m;
        Bf2[kc] = *(const short8*)&Wt2[c * 128 + (((kc * 4 + q) ^ (c & 15)) << 3)];
    }

    // ---- h-pack: lane (q,m) holds h[node m][F..F+3], F = wave*32 + f2*16 + q*4 ----
    {
        uint2* h2 = (uint2*)h4;
        {   // f2 = 0
            const int F = wave * 32 + q * 4;
            const float4 bb = *(const float4*)(db1 + F);
            uint2 hv;
            hv.x = pack2(fmaxf(at0[0] + bb.x, 0.f), fmaxf(at0[1] + bb.y, 0.f));
            hv.y = pack2(fmaxf(at0[2] + bb.z, 0.f), fmaxf(at0[3] + bb.w, 0.f));
            const int cf = wave * 4 + (q >> 1);           // 16B chunk index F/8
            h2[m * 32 + (((cf ^ m) << 1) | (q & 1))] = hv;
        }
        {   // f2 = 1
            const int F = wave * 32 + 16 + q * 4;
            const float4 bb = *(const float4*)(db1 + F);
            uint2 hv;
            hv.x = pack2(fmaxf(at1[0] + bb.x, 0.f), fmaxf(at1[1] + bb.y, 0.f));
            hv.y = pack2(fmaxf(at1[2] + bb.z, 0.f), fmaxf(at1[3] + bb.w, 0.f));
            const int cf = wave * 4 + 2 + (q >> 1);
            h2[m * 32 + (((cf ^ m) << 1) | (q & 1))] = hv;
        }
    }
    __syncthreads();

    // ---- gemm2: 16 nodes x 64 outs, K=128; wave w owns cols [w*16, w*16+16) ----
    f32x4 a2 = (f32x4){0.f, 0.f, 0.f, 0.f};
    #pragma unroll
    for (int kc = 0; kc < 4; kc++) {
        short8 af = *(const short8*)&h4[m * 16 + ((q + kc * 4) ^ m)];
        a2 = __builtin_amdgcn_mfma_f32_16x16x32_bf16(af, Bf2[kc], a2, 0, 0, 0);
    }

    const int c = wave * 16 + m;
    const float bv = db2[c];
    #pragma unroll
    for (int r = 0; r < 4; r++) {
        const int row = bid * 16 + q * 4 + r;
        float t = a2[r] + bv;
        t = 1.f / (1.f + __expf(-t));
        outp[(size_t)row * 64 + c] = t;
    }
}

// ---------- launch ----------
extern "C" void kernel_launch(void* const* d_in, const int* in_sizes, int n_in,
                              void* d_out, int out_size, void* d_ws, size_t ws_size,
                              hipStream_t stream)
{
    const float* x      = (const float*)d_in[0];
    const int*   ei     = (const int*)d_in[1];
    const float* enc_w1 = (const float*)d_in[2];
    const float* enc_b1 = (const float*)d_in[3];
    const float* enc_w2 = (const float*)d_in[4];
    const float* enc_b2 = (const float*)d_in[5];
    const float* w_c1   = (const float*)d_in[6];
    const float* b_c1   = (const float*)d_in[7];
    const float* w_c2   = (const float*)d_in[8];
    const float* b_c2   = (const float*)d_in[9];
    const float* w_c3   = (const float*)d_in[10];
    const float* b_c3   = (const float*)d_in[11];
    const float* dec_w1 = (const float*)d_in[12];
    const float* dec_b1 = (const float*)d_in[13];
    const float* dec_w2 = (const float*)d_in[14];
    const float* dec_b2 = (const float*)d_in[15];

    const int* src = ei;
    const int* dst = ei + NE;

    const int NP = 50048;  // rows padded to multiple of 64 (k1 enc1 tiles)

    char* ws = (char*)d_ws;
    size_t o = 0;
    auto alloc = [&](size_t bytes) -> void* {
        void* p = ws + o;
        o = (o + bytes + 255) & ~(size_t)255;
        return p;
    };
    int*   gcnt = (int*)alloc(256 * 4);
    int*   off  = (int*)alloc((size_t)(NN + 1) * 4);
    unsigned short* csr = (unsigned short*)alloc((size_t)NE * 2);
    unsigned int* bucket = (unsigned int*)alloc((size_t)NBKT * BCAP * 4);  // 4 MB
    float* dinv = (float*)alloc((size_t)NN * 4);
    unsigned short* bufA = (unsigned short*)alloc((size_t)NP * HD * 2);
    unsigned short* bufB = (unsigned short*)alloc((size_t)NP * HD * 2);
    unsigned short* t1 = (unsigned short*)alloc(128 * 128 * 2);  // enc_w2^T
    unsigned short* t2 = (unsigned short*)alloc(128 * 128 * 2);  // w_c1^T
    unsigned short* t3 = (unsigned short*)alloc(128 * 128 * 2);  // w_c2^T
    unsigned short* t4 = (unsigned short*)alloc(128 * 128 * 2);  // w_c3^T
    unsigned short* t5 = (unsigned short*)alloc(128 * 128 * 2);  // dec_w1^T
    unsigned short* t6 = (unsigned short*)alloc(128 * 64 * 2);   // dec_w2^T
    (void)ws_size; (void)n_in; (void)in_sizes; (void)out_size;

    hipMemsetAsync(gcnt, 0, 256 * 4, stream);

    const int PB   = (NE + P1E - 1) / P1E;  // 196 pass-1 blocks
    const int GB   = NP / 64;               // 782 enc1 row-tiles
    const int GB16 = NN / 16;               // 3125 16-row tiles

    // enc1 (inline W-convert) ∥ pass 1 ∥ t1-t6 transposes
    k1_k<<<GB + PB + 352, 256, 0, stream>>>(x, enc_w1, enc_b1, bufA, src, dst, gcnt, bucket,
                                            enc_w2, w_c1, w_c2, w_c3, dec_w1, dec_w2,
                                            t1, t2, t3, t4, t5, t6, GB, PB);
    // enc2+conv1 fused ∥ pass 2 -> bufB = h2@w_c1 (UNSCALED), off/dinv/csr
    k2f_k<<<GB16 + NBKT, 256, 0, stream>>>(bufA, t1, enc_b2, t2, bufB,
                                           gcnt, bucket, off, dinv, csr, GB16);
    // conv2: WEIGHTED gather (dinv[src] per edge) -> bufA = dinv ⊙ g@w_c2
    aggm16_k<true><<<GB16, 256, 0, stream>>>((const uint4*)bufB, off, csr, dinv, b_c1, t3, bufA);
    // conv3: unweighted gather (input pre-scaled) -> bufB = dinv ⊙ g@w_c3
    aggm16_k<false><<<GB16, 256, 0, stream>>>((const uint4*)bufA, off, csr, dinv, b_c2, t4, bufB);
    // decoder fused: agg(b_c3) -> dec1 relu -> dec2 sigmoid -> d_out
    decf16_k<<<GB16, 256, 0, stream>>>((const uint4*)bufB, off, csr, dinv, b_c3,
                                       t5, dec_b1, t6, dec_b2, (float*)d_out);
}

// Round 8
// 261.963 us; speedup vs baseline: 1.0720x; 1.0720x over previous
//
#include <hip/hip_runtime.h>
#include <stdint.h>

#define NN 50000
#define NE 800000
#define FD 64
#define HD 128
#define NBKT 196          // (NN+255)/256 coarse buckets (256 nodes each)
#define BCAP 5120         // per-bucket capacity (avg 4096, generous slack)
#define P1E 4096          // edges per pass-1 block (196 blocks: sort parallelism)

static_assert(NN % 16 == 0, "16-row tiles are exact");

typedef __attribute__((ext_vector_type(8))) short short8;   // 8 bf16 (4 VGPRs)
typedef __attribute__((ext_vector_type(4))) float f32x4;    // MFMA acc

#define AS1 __attribute__((address_space(1)))
#define AS3 __attribute__((address_space(3)))

// ---------- bf16 helpers ----------
__device__ __forceinline__ float bflo(unsigned int v) {
    union { unsigned int u; float f; } c; c.u = v << 16; return c.f;
}
__device__ __forceinline__ float bfhi(unsigned int v) {
    union { unsigned int u; float f; } c; c.u = v & 0xffff0000u; return c.f;
}
__device__ __forceinline__ unsigned short f2bf(float f) {
    union { float f; unsigned int u; } c; c.f = f;
    unsigned int u = c.u;
    return (unsigned short)((u + 0x7fffu + ((u >> 16) & 1u)) >> 16);
}
__device__ __forceinline__ unsigned int pack2(float a, float b) {
    return (unsigned int)f2bf(a) | ((unsigned int)f2bf(b) << 16);
}

// ---------- 256-thread inclusive scan via wave64 shuffles (2 barriers, not 16) ----------
__device__ __forceinline__ void scan256(int v, int tid, int* __restrict__ out,
                                        int* __restrict__ wsum)
{
    int x = v;
    #pragma unroll
    for (int d = 1; d < 64; d <<= 1) {
        int y = __shfl_up(x, d, 64);
        if ((tid & 63) >= d) x += y;
    }
    if ((tid & 63) == 63) wsum[tid >> 6] = x;
    __syncthreads();
    int add = 0;
    #pragma unroll
    for (int w = 0; w < 4; w++) if (w < (tid >> 6)) add += wsum[w];
    out[tid] = x + add;
    __syncthreads();
}

// ---------- MFMA GEMM device body (WCVT = inline f32->bf16 swizzle of weights) ----------
template <int K, int COLS, int EPI, bool BIAS, bool RSCALE, bool A_F32, bool OUT_F32, bool WCVT>
__device__ __forceinline__ void mgemm_dev(
    int bid,
    const void* __restrict__ Av,
    const void* __restrict__ Wt,
    const float* __restrict__ bias,
    const float* __restrict__ dinv,
    void* __restrict__ outv, int nrows)
{
    constexpr int NB = COLS / 16;
    constexpr int KC = K / 32;
    constexpr int GMASK = (K >> 3) - 1;
    __shared__ __align__(16) unsigned char Ws8[COLS * K * 2];

    const int tid = threadIdx.x;
    const int wave = tid >> 6;
    const int lane = tid & 63;

    if constexpr (WCVT) {
        const float* wf = (const float*)Wt;
        unsigned short* ws = (unsigned short*)Ws8;
        #pragma unroll
        for (int i = 0; i < K * COLS / 256; i++) {
            const int e = i * 256 + tid;
            const int k = e / COLS, c = e % COLS;
            const int gsw = (k >> 3) ^ (c & GMASK);
            ws[c * K + gsw * 8 + (k & 7)] = f2bf(wf[e]);
        }
    } else {
        constexpr int ROUNDS = COLS * K * 2 / 4096;
        const int gb = wave * 1024 + lane * 16;
        const int lb = wave * 1024;
        #pragma unroll
        for (int r = 0; r < ROUNDS; r++) {
            __builtin_amdgcn_global_load_lds(
                (const AS1 unsigned int*)((const unsigned char*)Wt + r * 4096 + gb),
                (AS3 unsigned int*)(Ws8 + r * 4096 + lb),
                16, 0, 0);
        }
    }

    const int m = lane & 15;
    const int q = lane >> 4;
    const int row0 = bid * 64 + wave * 16;

    f32x4 acc[NB];
    #pragma unroll
    for (int i = 0; i < NB; i++) acc[i] = (f32x4){0.f, 0.f, 0.f, 0.f};

    const bool arow_ok = !A_F32 || (row0 + m) < nrows;

    short8 af[KC];
    #pragma unroll
    for (int kc = 0; kc < KC; kc++) {
        if constexpr (A_F32) {
            const float* arowf = (const float*)Av + (size_t)(row0 + m) * K + q * 8 + kc * 32;
            float4 lo = make_float4(0.f, 0.f, 0.f, 0.f), hi = lo;
            if (arow_ok) { lo = *(const float4*)arowf; hi = *(const float4*)(arowf + 4); }
            af[kc][0] = (short)f2bf(lo.x); af[kc][1] = (short)f2bf(lo.y);
            af[kc][2] = (short)f2bf(lo.z); af[kc][3] = (short)f2bf(lo.w);
            af[kc][4] = (short)f2bf(hi.x); af[kc][5] = (short)f2bf(hi.y);
            af[kc][6] = (short)f2bf(hi.z); af[kc][7] = (short)f2bf(hi.w);
        } else {
            const unsigned short* arow = (const unsigned short*)Av + (size_t)(row0 + m) * K + q * 8 + kc * 32;
            af[kc] = *(const short8*)arow;
        }
    }
    __syncthreads();

    #pragma unroll
    for (int kc = 0; kc < KC; kc++) {
        #pragma unroll
        for (int nb = 0; nb < NB; nb++) {
            const int c = nb * 16 + m;
            const int gsw = (kc * 4 + q) ^ (c & GMASK);
            short8 bf = *(const short8*)&Ws8[(c * K + gsw * 8) * 2];
            acc[nb] = __builtin_amdgcn_mfma_f32_16x16x32_bf16(af[kc], bf, acc[nb], 0, 0, 0);
        }
    }

    float bv[NB];
    #pragma unroll
    for (int nb = 0; nb < NB; nb++) bv[nb] = BIAS ? bias[nb * 16 + m] : 0.f;

    #pragma unroll
    for (int r = 0; r < 4; r++) {
        int row = row0 + q * 4 + r;
        if (row < nrows) {
            float sc = RSCALE ? dinv[row] : 1.f;
            #pragma unroll
            for (int nb = 0; nb < NB; nb++) {
                float t = acc[nb][r];
                if (RSCALE) t *= sc;
                t += bv[nb];
                if (EPI == 1) t = fmaxf(t, 0.f);
                if (EPI == 2) t = 1.f / (1.f + __expf(-t));
                if constexpr (OUT_F32) {
                    ((float*)outv)[(size_t)row * COLS + nb * 16 + m] = t;
                } else {
                    ((unsigned short*)outv)[(size_t)row * COLS + nb * 16 + m] = f2bf(t);
                }
            }
        }
    }
}

// plain mgemm wrapper
template <int K, int COLS, int EPI, bool BIAS, bool RSCALE, bool A_F32, bool OUT_F32>
__global__ __launch_bounds__(256) void mgemm_k(
    const void* __restrict__ Av, const unsigned short* __restrict__ Wt,
    const float* __restrict__ bias, const float* __restrict__ dinv,
    void* __restrict__ outv, int nrows)
{
    mgemm_dev<K, COLS, EPI, BIAS, RSCALE, A_F32, OUT_F32, false>(blockIdx.x, Av, Wt, bias, dinv, outv, nrows);
}

// ---------- K1: enc1-mgemm (inline W-convert) ∥ counting-sort pass 1 ∥ t1-t6 transposes ----------
// Entry pack: src(16b) | dlow(8b)<<16 | bkt(8b)<<24.
__global__ __launch_bounds__(256) void k1_k(
    const float* __restrict__ x, const float* __restrict__ w0,
    const float* __restrict__ enc_b1, unsigned short* __restrict__ bufA,
    const int* __restrict__ src, const int* __restrict__ dst,
    int* __restrict__ gcnt, unsigned int* __restrict__ bucket,
    const float* __restrict__ w1, const float* __restrict__ w2,
    const float* __restrict__ w3, const float* __restrict__ w4,
    const float* __restrict__ w5, const float* __restrict__ w6,
    unsigned short* __restrict__ t1, unsigned short* __restrict__ t2,
    unsigned short* __restrict__ t3, unsigned short* __restrict__ t4,
    unsigned short* __restrict__ t5, unsigned short* __restrict__ t6,
    int gb, int pb)
{
    const int b = blockIdx.x;
    if (b < gb) {
        mgemm_dev<64, 128, 1, true, false, true, false, true>(b, x, w0, enc_b1, nullptr, bufA, NN);
    } else if (b < gb + pb) {
        __shared__ int lcnt[256], lsw[256], lexc[256], lofs[256], lrank[256];
        __shared__ int wsb[4];
        __shared__ unsigned int stage[P1E];
        const int tid = threadIdx.x;
        const int bb = b - gb;
        lcnt[tid] = 0; lrank[tid] = 0;
        __syncthreads();
        unsigned int ent[P1E / 256];
        #pragma unroll
        for (int u = 0; u < P1E / 256; u++) {
            int g = bb * P1E + u * 256 + tid;
            if (g < NE) {
                int d = dst[g], s = src[g];
                int bk = d >> 8;
                atomicAdd(&lcnt[bk], 1);
                ent[u] = (unsigned int)s | ((unsigned int)(d & 255) << 16)
                       | ((unsigned int)bk << 24);
            } else ent[u] = 0xFFFFFFFFu;
        }
        __syncthreads();
        const int v = lcnt[tid];
        scan256(v, tid, lsw, wsb);
        lexc[tid] = lsw[tid] - v;
        lofs[tid] = (v > 0) ? atomicAdd(&gcnt[tid], v) : 0;
        __syncthreads();
        #pragma unroll
        for (int u = 0; u < P1E / 256; u++) {
            if (ent[u] != 0xFFFFFFFFu) {
                int bk = ent[u] >> 24;
                int r = atomicAdd(&lrank[bk], 1);
                stage[lexc[bk] + r] = ent[u];
            }
        }
        __syncthreads();
        int cb = NE - bb * P1E; if (cb > P1E) cb = P1E;
        for (int i = tid; i < cb; i += 256) {
            unsigned int e = stage[i];
            int bk = e >> 24;
            bucket[(size_t)bk * BCAP + lofs[bk] + (i - lexc[bk])] = e;
        }
    } else {
        int b2 = b - gb - pb;       // 352 transpose blocks
        const float* W; unsigned short* T; int C = 128;
        if      (b2 <  64) { W = w1; T = t1; }
        else if (b2 < 128) { W = w2; T = t2; b2 -= 64; }
        else if (b2 < 192) { W = w3; T = t3; b2 -= 128; }
        else if (b2 < 256) { W = w4; T = t4; b2 -= 192; }
        else if (b2 < 320) { W = w5; T = t5; b2 -= 256; }
        else               { W = w6; T = t6; b2 -= 320; C = 64; }
        int e = b2 * 256 + threadIdx.x;
        int k, c;
        if (C == 128) { k = e >> 7; c = e & 127; } else { k = e >> 6; c = e & 63; }
        int gsw = (k >> 3) ^ (c & 15);   // K=128 -> gmask 15
        T[c * 128 + gsw * 8 + (k & 7)] = f2bf(W[e]);
    }
}

// ---------- K2: enc2-mgemm ∥ pass 2 (gcnt scan -> absolute off, dinv, CSR) ----------
__global__ __launch_bounds__(256) void k2_k(
    const unsigned short* __restrict__ bufA, const unsigned short* __restrict__ t1,
    const float* __restrict__ enc_b2, unsigned short* __restrict__ bufB,
    const int* __restrict__ gcnt, const unsigned int* __restrict__ bucket,
    int* __restrict__ off, float* __restrict__ dinv,
    unsigned short* __restrict__ csr, int gb)
{
    if ((int)blockIdx.x < gb) {
        mgemm_dev<128, 128, 0, true, false, false, false, false>(blockIdx.x, bufA, t1, enc_b2, nullptr, bufB, NN);
    } else {
        __shared__ int lc[256], sw[256], sexc[256], lr[256], gsh[256];
        __shared__ int wsb[4];
        const int tid = threadIdx.x;
        const int b = blockIdx.x - gb;
        // inclusive scan of gcnt -> bucket base (uniform)
        const int gv = (tid < NBKT) ? gcnt[tid] : 0;
        scan256(gv, tid, gsh, wsb);
        const int cb = gcnt[b];
        const int base = gsh[b] - cb;
        unsigned int ent[BCAP / 256];
        #pragma unroll
        for (int u = 0; u < BCAP / 256; u++) {
            int i = u * 256 + tid;
            ent[u] = (i < cb) ? bucket[(size_t)b * BCAP + i] : 0xFFFFFFFFu;
        }
        lc[tid] = 0; lr[tid] = 0;
        __syncthreads();
        #pragma unroll
        for (int u = 0; u < BCAP / 256; u++)
            if (ent[u] != 0xFFFFFFFFu) atomicAdd(&lc[(ent[u] >> 16) & 255], 1);
        __syncthreads();
        const int v = lc[tid];
        const int node = b * 256 + tid;
        if (node < NN) dinv[node] = rsqrtf((float)(v + 1));  // +1 self-loop
        scan256(v, tid, sw, wsb);
        sexc[tid] = sw[tid] - v;
        if (node < NN) off[node] = base + sexc[tid];         // absolute offset
        if (b == NBKT - 1 && tid == 0) off[NN] = NE;
        __syncthreads();
        #pragma unroll
        for (int u = 0; u < BCAP / 256; u++) {
            if (ent[u] != 0xFFFFFFFFu) {
                int dl = (ent[u] >> 16) & 255;
                int r = atomicAdd(&lr[dl], 1);
                csr[base + sexc[dl] + r] = (unsigned short)(ent[u] & 0xffff);
            }
        }
    }
}

// ---------- gather, one node per 16-lane group (round-2/4 proven plain form) ----------
__device__ __forceinline__ void gather16_dev(
    const uint4* __restrict__ hws, const int* __restrict__ off,
    const unsigned short* __restrict__ csr, const float* __restrict__ dinv,
    const float* __restrict__ gbias, uint4* __restrict__ g4, int bid, int tid)
{
    const int g = tid >> 4;     // 0..15 = row in tile
    const int l = tid & 15;     // feature chunk (8 bf16)
    const int row = bid * 16 + g;               // always < NN (exact grid)
    const float4 b0 = *(const float4*)(gbias + 8 * l);
    const float4 b1 = *(const float4*)(gbias + 8 * l + 4);

    uint4 v = hws[(size_t)row * 16 + l];        // self-loop term
    float s0 = bflo(v.x), s1 = bfhi(v.x), s2 = bflo(v.y), s3 = bfhi(v.y);
    float s4 = bflo(v.z), s5 = bfhi(v.z), s6 = bflo(v.w), s7 = bfhi(v.w);
    const int je = off[row + 1];
    int j = off[row];
    for (; j + 8 <= je; j += 8) {
        uint4 t[8];
        #pragma unroll
        for (int u = 0; u < 8; u++) t[u] = hws[(size_t)csr[j + u] * 16 + l];
        #pragma unroll
        for (int u = 0; u < 8; u++) {
            s0 += bflo(t[u].x); s1 += bfhi(t[u].x);
            s2 += bflo(t[u].y); s3 += bfhi(t[u].y);
            s4 += bflo(t[u].z); s5 += bfhi(t[u].z);
            s6 += bflo(t[u].w); s7 += bfhi(t[u].w);
        }
    }
    for (; j < je; j++) {
        uint4 t = hws[(size_t)csr[j] * 16 + l];
        s0 += bflo(t.x); s1 += bfhi(t.x);
        s2 += bflo(t.y); s3 += bfhi(t.y);
        s4 += bflo(t.z); s5 += bfhi(t.z);
        s6 += bflo(t.w); s7 += bfhi(t.w);
    }
    const float di = dinv[row];
    uint4 o;
    o.x = pack2(fmaxf(fmaf(di, s0, b0.x), 0.f), fmaxf(fmaf(di, s1, b0.y), 0.f));
    o.y = pack2(fmaxf(fmaf(di, s2, b0.z), 0.f), fmaxf(fmaf(di, s3, b0.w), 0.f));
    o.z = pack2(fmaxf(fmaf(di, s4, b1.x), 0.f), fmaxf(fmaf(di, s5, b1.y), 0.f));
    o.w = pack2(fmaxf(fmaf(di, s6, b1.z), 0.f), fmaxf(fmaf(di, s7, b1.w), 0.f));
    g4[g * 16 + (l ^ g)] = o;   // chunk l of row g stored at slot l^g
}

// ---------- fused agg + conv-GEMM, 16-row tiles (round-4 champion form) ----------
template <int EPI, bool BIAS, bool RSCALE>
__global__ __launch_bounds__(256) void aggm16_k(
    const uint4* __restrict__ hws, const int* __restrict__ off,
    const unsigned short* __restrict__ csr, const float* __restrict__ dinv,
    const float* __restrict__ gbias,          // gather bias (b_c*)
    const unsigned short* __restrict__ Wt,    // W^T, XOR-swizzled layout (gmask 15)
    const float* __restrict__ obias,          // epilogue bias or nullptr
    unsigned short* __restrict__ out)
{
    __shared__ __align__(16) uint4 g4[16 * 16];   // 4 KB A-tile

    const int tid = threadIdx.x;
    const int bid = blockIdx.x;
    const int wave = tid >> 6;
    const int lane = tid & 63;
    const int m = lane & 15;
    const int q = lane >> 4;

    // prestage B fragments (issued before gather; latency hidden under it)
    short8 Bf0[4], Bf1[4];
    #pragma unroll
    for (int kc = 0; kc < 4; kc++) {
        const int c0 = wave * 32 + m;
        const int c1 = c0 + 16;
        Bf0[kc] = *(const short8*)&Wt[c0 * 128 + (((kc * 4 + q) ^ (c0 & 15)) << 3)];
        Bf1[kc] = *(const short8*)&Wt[c1 * 128 + (((kc * 4 + q) ^ (c1 & 15)) << 3)];
    }

    gather16_dev(hws, off, csr, dinv, gbias, g4, bid, tid);
    __syncthreads();

    // ---- GEMM: 16 rows x 128 cols, wave w owns cols [w*32, w*32+32) ----
    f32x4 a0 = (f32x4){0.f, 0.f, 0.f, 0.f}, a1 = a0;
    #pragma unroll
    for (int kc = 0; kc < 4; kc++) {
        short8 af = *(const short8*)&g4[m * 16 + ((q + kc * 4) ^ m)];
        a0 = __builtin_amdgcn_mfma_f32_16x16x32_bf16(af, Bf0[kc], a0, 0, 0, 0);
        a1 = __builtin_amdgcn_mfma_f32_16x16x32_bf16(af, Bf1[kc], a1, 0, 0, 0);
    }

    const int c0 = wave * 32 + m;
    const int c1 = c0 + 16;
    const float bv0 = BIAS ? obias[c0] : 0.f;
    const float bv1 = BIAS ? obias[c1] : 0.f;

    #pragma unroll
    for (int r = 0; r < 4; r++) {
        const int row = bid * 16 + q * 4 + r;
        const float sc = RSCALE ? dinv[row] : 1.f;
        float t0 = a0[r], t1 = a1[r];
        if (RSCALE) { t0 *= sc; t1 *= sc; }
        t0 += bv0; t1 += bv1;
        if (EPI == 1) { t0 = fmaxf(t0, 0.f); t1 = fmaxf(t1, 0.f); }
        out[(size_t)row * 128 + c0] = f2bf(t0);
        out[(size_t)row * 128 + c1] = f2bf(t1);
    }
}

// ---------- fused agg + full decoder (dec1 relu + dec2 sigmoid), 16-row tiles ----------
__global__ __launch_bounds__(256) void decf16_k(
    const uint4* __restrict__ hws, const int* __restrict__ off,
    const unsigned short* __restrict__ csr, const float* __restrict__ dinv,
    const float* __restrict__ gbias,          // b_c3
    const unsigned short* __restrict__ Wt1,   // dec_w1^T swizzled (128 cols)
    const float* __restrict__ db1,
    const unsigned short* __restrict__ Wt2,   // dec_w2^T swizzled (64 cols)
    const float* __restrict__ db2,
    float* __restrict__ outp)
{
    __shared__ __align__(16) uint4 g4[16 * 16];   // 4 KB gather tile
    __shared__ __align__(16) uint4 h4[16 * 16];   // 4 KB h tile

    const int tid = threadIdx.x;
    const int bid = blockIdx.x;
    const int wave = tid >> 6;
    const int lane = tid & 63;
    const int m = lane & 15;
    const int q = lane >> 4;

    // prestage dec_w1^T fragments (A'-operand of transposed product)
    short8 Wf0[4], Wf1[4];
    #pragma unroll
    for (int kc = 0; kc < 4; kc++) {
        const int c0 = wave * 32 + m;
        const int c1 = c0 + 16;
        Wf0[kc] = *(const short8*)&Wt1[c0 * 128 + (((kc * 4 + q) ^ (c0 & 15)) << 3)];
        Wf1[kc] = *(const short8*)&Wt1[c1 * 128 + (((kc * 4 + q) ^ (c1 & 15)) << 3)];
    }

    gather16_dev(hws, off, csr, dinv, gbias, g4, bid, tid);
    __syncthreads();

    // ---- gemm1 (transposed): wave owns features [wave*32, wave*32+32) x 16 nodes ----
    f32x4 at0 = (f32x4){0.f, 0.f, 0.f, 0.f}, at1 = at0;
    #pragma unroll
    for (int kc = 0; kc < 4; kc++) {
        short8 gf = *(const short8*)&g4[m * 16 + ((q + kc * 4) ^ m)];
        at0 = __builtin_amdgcn_mfma_f32_16x16x32_bf16(Wf0[kc], gf, at0, 0, 0, 0);
        at1 = __builtin_amdgcn_mfma_f32_16x16x32_bf16(Wf1[kc], gf, at1, 0, 0, 0);
    }

    // prestage dec_w2^T B fragments (global, L2-hot; hidden under h-pack)
    short8 Bf2[4];
    #pragma unroll
    for (int kc = 0; kc < 4; kc++) {
        const int c = wave * 16 + m;
        Bf2[kc] = *(const short8*)&Wt2[c * 128 + (((kc * 4 + q) ^ (c & 15)) << 3)];
    }

    // ---- h-pack: lane (q,m) holds h[node m][F..F+3], F = wave*32 + f2*16 + q*4 ----
    {
        uint2* h2 = (uint2*)h4;
        {   // f2 = 0
            const int F = wave * 32 + q * 4;
            const float4 bb = *(const float4*)(db1 + F);
            uint2 hv;
            hv.x = pack2(fmaxf(at0[0] + bb.x, 0.f), fmaxf(at0[1] + bb.y, 0.f));
            hv.y = pack2(fmaxf(at0[2] + bb.z, 0.f), fmaxf(at0[3] + bb.w, 0.f));
            const int cf = wave * 4 + (q >> 1);           // 16B chunk index F/8
            h2[m * 32 + (((cf ^ m) << 1) | (q & 1))] = hv;
        }
        {   // f2 = 1
            const int F = wave * 32 + 16 + q * 4;
            const float4 bb = *(const float4*)(db1 + F);
            uint2 hv;
            hv.x = pack2(fmaxf(at1[0] + bb.x, 0.f), fmaxf(at1[1] + bb.y, 0.f));
            hv.y = pack2(fmaxf(at1[2] + bb.z, 0.f), fmaxf(at1[3] + bb.w, 0.f));
            const int cf = wave * 4 + 2 + (q >> 1);
            h2[m * 32 + (((cf ^ m) << 1) | (q & 1))] = hv;
        }
    }
    __syncthreads();

    // ---- gemm2: 16 nodes x 64 outs, K=128; wave w owns cols [w*16, w*16+16) ----
    f32x4 a2 = (f32x4){0.f, 0.f, 0.f, 0.f};
    #pragma unroll
    for (int kc = 0; kc < 4; kc++) {
        short8 af = *(const short8*)&h4[m * 16 + ((q + kc * 4) ^ m)];
        a2 = __builtin_amdgcn_mfma_f32_16x16x32_bf16(af, Bf2[kc], a2, 0, 0, 0);
    }

    const int c = wave * 16 + m;
    const float bv = db2[c];
    #pragma unroll
    for (int r = 0; r < 4; r++) {
        const int row = bid * 16 + q * 4 + r;
        float t = a2[r] + bv;
        t = 1.f / (1.f + __expf(-t));
        outp[(size_t)row * 64 + c] = t;
    }
}

// ---------- launch ----------
extern "C" void kernel_launch(void* const* d_in, const int* in_sizes, int n_in,
                              void* d_out, int out_size, void* d_ws, size_t ws_size,
                              hipStream_t stream)
{
    const float* x      = (const float*)d_in[0];
    const int*   ei     = (const int*)d_in[1];
    const float* enc_w1 = (const float*)d_in[2];
    const float* enc_b1 = (const float*)d_in[3];
    const float* enc_w2 = (const float*)d_in[4];
    const float* enc_b2 = (const float*)d_in[5];
    const float* w_c1   = (const float*)d_in[6];
    const float* b_c1   = (const float*)d_in[7];
    const float* w_c2   = (const float*)d_in[8];
    const float* b_c2   = (const float*)d_in[9];
    const float* w_c3   = (const float*)d_in[10];
    const float* b_c3   = (const float*)d_in[11];
    const float* dec_w1 = (const float*)d_in[12];
    const float* dec_b1 = (const float*)d_in[13];
    const float* dec_w2 = (const float*)d_in[14];
    const float* dec_b2 = (const float*)d_in[15];

    const int* src = ei;
    const int* dst = ei + NE;

    const int NP = 50048;  // rows padded to multiple of 64 (mgemm tiles)

    char* ws = (char*)d_ws;
    size_t o = 0;
    auto alloc = [&](size_t bytes) -> void* {
        void* p = ws + o;
        o = (o + bytes + 255) & ~(size_t)255;
        return p;
    };
    int*   gcnt = (int*)alloc(256 * 4);
    int*   off  = (int*)alloc((size_t)(NN + 1) * 4);
    unsigned short* csr = (unsigned short*)alloc((size_t)NE * 2);
    unsigned int* bucket = (unsigned int*)alloc((size_t)NBKT * BCAP * 4);  // 4 MB
    float* dinv = (float*)alloc((size_t)NN * 4);
    unsigned short* bufA = (unsigned short*)alloc((size_t)NP * HD * 2);
    unsigned short* bufB = (unsigned short*)alloc((size_t)NP * HD * 2);
    unsigned short* t1 = (unsigned short*)alloc(128 * 128 * 2);  // enc_w2^T
    unsigned short* t2 = (unsigned short*)alloc(128 * 128 * 2);  // w_c1^T
    unsigned short* t3 = (unsigned short*)alloc(128 * 128 * 2);  // w_c2^T
    unsigned short* t4 = (unsigned short*)alloc(128 * 128 * 2);  // w_c3^T
    unsigned short* t5 = (unsigned short*)alloc(128 * 128 * 2);  // dec_w1^T
    unsigned short* t6 = (unsigned short*)alloc(128 * 64 * 2);   // dec_w2^T
    (void)ws_size; (void)n_in; (void)in_sizes; (void)out_size;

    hipMemsetAsync(gcnt, 0, 256 * 4, stream);

    const int PB   = (NE + P1E - 1) / P1E;  // 196 pass-1 blocks
    const int GB   = NP / 64;               // 782 mgemm row-tiles
    const int GB16 = NN / 16;               // 3125 fused agg+gemm tiles

    // enc1 (inline W-convert) ∥ pass 1 ∥ t1-t6 transposes
    k1_k<<<GB + PB + 352, 256, 0, stream>>>(x, enc_w1, enc_b1, bufA, src, dst, gcnt, bucket,
                                            enc_w2, w_c1, w_c2, w_c3, dec_w1, dec_w2,
                                            t1, t2, t3, t4, t5, t6, GB, PB);
    // enc2 ∥ pass 2 (absolute off + dinv + CSR)
    k2_k<<<GB + NBKT, 256, 0, stream>>>(bufA, t1, enc_b2, bufB, gcnt, bucket,
                                        off, dinv, csr, GB);
    // conv1 GEMM: bufB(h1) -> bufA(hws1 = dinv ⊙ h1 W)
    mgemm_k<128, 128, 0, false, true, false, false><<<GB, 256, 0, stream>>>(bufB, t2, nullptr, dinv, bufA, NN);
    // conv2 fused: agg(hws1,b_c1,relu) -> g ; bufB = dinv ⊙ g@w_c2
    aggm16_k<0, false, true><<<GB16, 256, 0, stream>>>((const uint4*)bufA, off, csr, dinv, b_c1, t3, nullptr, bufB);
    // conv3 fused: -> bufA = dinv ⊙ g@w_c3
    aggm16_k<0, false, true><<<GB16, 256, 0, stream>>>((const uint4*)bufB, off, csr, dinv, b_c2, t4, nullptr, bufA);
    // decoder fused: agg(hws3,b_c3,relu) -> dec1 relu -> dec2 sigmoid -> d_out
    decf16_k<<<GB16, 256, 0, stream>>>((const uint4*)bufA, off, csr, dinv, b_c3,
                                       t5, dec_b1, t6, dec_b2, (float*)d_out);
}